// Round 19
// baseline (71.093 us; speedup 1.0000x reference)
//
#include <hip/hip_runtime.h>

#define BB 128
#define LL 336
#define CC 862
#define PRED 96
#define WIN 12
#define S_IN 28
#define S_OUT 8
#define CT 128
#define NTILES 7                       // ceil(862/128)
#define NCH 14                         // s-chunks of 2 windows (24 rows)
#define LSTR 25                        // LDS per-channel stride (odd -> conflict-free reads)

#define SQRT12F 3.4641016151377544f

// -Sb(t)/sqrt(12), Sb(t) = 2*sum_{k=1..5} sin(pi*k*t/6)   (exact closed forms)
__device__ const float COEFP[12] = {
    0.0f, -2.1547005383792515f, 0.0f, -0.5773502691896258f,
    0.0f, -0.15470053837925146f, 0.0f, 0.15470053837925146f,
    0.0f,  0.5773502691896258f, 0.0f,  2.1547005383792515f
};

// ---- prep kernels ----

// wq4[((s*4 + pg)*CC + c)] (float4) = { wA[c][pg][s], wP[c][pg][s],
//                                       wA[c][pg+4][s], wP[c][pg+4][s] }
// -> thread (c, pg) reads ONE coalesced b128 per s covering both its p's.
__global__ void prep_wq4(const float* __restrict__ wA, const float* __restrict__ wP,
                         float* __restrict__ wq4) {
    int i = blockIdx.x * 256 + threadIdx.x;          // i = ((s*4+pg)*CC + c)*4 + j
    if (i >= S_IN * 4 * CC * 4) return;
    int j  = i & 3;
    int c  = (i >> 2) % CC;
    int pg = (i / (4 * CC)) & 3;
    int s  = i / (16 * CC);
    int p  = pg + 4 * (j >> 1);
    int src = (c * S_OUT + p) * S_IN + s;
    wq4[i] = (j & 1) ? wP[src] : wA[src];
}

__global__ void prep_mcoef(const float* __restrict__ wA, float* __restrict__ mcoefT) {
    int i = blockIdx.x * 256 + threadIdx.x;          // [p][c]
    if (i >= S_OUT * CC) return;
    int c = i % CC;
    int p = i / CC;
    float s = 0.f;
    for (int k = 0; k < S_IN; ++k) s += wA[(c * S_OUT + p) * S_IN + k];
    mcoefT[i] = 1.0f - s;
}

__global__ void prep_bias(const float* __restrict__ bA, const float* __restrict__ bP,
                          float* __restrict__ biasv) {
    int i = blockIdx.x * 256 + threadIdx.x;          // [t][p][c]
    if (i >= 12 * S_OUT * CC) return;
    int c = i % CC;
    int tp = i / CC;
    int p = tp % S_OUT;
    int t = tp / S_OUT;
    float v = COEFP[t] * bP[c * S_OUT + p];
    if (t == 0) v += SQRT12F * bA[c * S_OUT + p];
    biasv[i] = v;
}

// ---- fused main kernel ----
// Exactly the r16 structure (CT=128: 512-B granules; 24-row chunks; single
// buffer; 2 barriers/chunk — r17 dbuf and r18 big-chunk both regressed).
// Changes: launch_bounds(512,8) (r16's (512,4) capped residency at 2 blocks/CU;
// now 4 blocks/CU, VGPR cap 64 — body compiles ~52-64) and float4 weight loads
// (28 b128 instead of 56 b64 per thread).

template <bool TRANS>
__global__ __launch_bounds__(512, 8) void fused19(
    const float* __restrict__ x,
    const float* __restrict__ wq4,
    const float* __restrict__ mcoefT, const float* __restrict__ biasv,
    const float* __restrict__ wA_raw, const float* __restrict__ wP_raw,
    const float* __restrict__ bAr, const float* __restrict__ bPr,
    float* __restrict__ out)
{
    __shared__ float sl[CT * LSTR];    // 12800 B

    const int b   = blockIdx.y;
    const int c0  = blockIdx.x * CT;
    const int NC  = min(CT, CC - c0);  // 128 or 94 (even)
    const int tid = threadIdx.x;       // 0..511

    // staging map: one wave = one full 512-B row segment (64 float2)
    const int slot  = tid & 63;
    const int rbase = tid >> 6;        // 0..7
    const int col   = 2 * slot;
    const int csrc  = (col + 1 < NC) ? col : (NC - 2);
    const float* xb = x + ((size_t)b * LL) * CC + c0 + csrc;

    // compute map
    const int cc = tid & 127;
    const int pg = tid >> 7;           // 0..3 -> p = pg, pg+4
    const int c  = c0 + cc;
    const bool act = (cc < NC);
    const int cl = act ? c : (CC - 1);

    // prologue: issue chunk 0 loads (rows 0..23)
    float2 vbuf[3];
    #pragma unroll
    for (int kk = 0; kk < 3; ++kk) {
        const int r = rbase + 8 * kk;
        vbuf[kk] = *reinterpret_cast<const float2*>(xb + (size_t)r * CC);
    }

    float A0[2] = {0.f, 0.f}, A6[2] = {0.f, 0.f};
    float Au[2][5] = {{0.f,0.f,0.f,0.f,0.f},{0.f,0.f,0.f,0.f,0.f}};
    float Pv[2][5] = {{0.f,0.f,0.f,0.f,0.f},{0.f,0.f,0.f,0.f,0.f}};
    float msum = 0.f;
    float sw[2] = {0.f, 0.f};          // fallback only

    const float4* wq = reinterpret_cast<const float4*>(wq4);

    #pragma unroll 1
    for (int k = 0; k < NCH; ++k) {
        __syncthreads();               // previous compute done reading sl
        #pragma unroll
        for (int kk = 0; kk < 3; ++kk) {
            const int r = rbase + 8 * kk;
            sl[col * LSTR + r]       = vbuf[kk].x;
            sl[(col + 1) * LSTR + r] = vbuf[kk].y;
        }
        __syncthreads();               // sl ready

        // prefetch next chunk (overlaps compute below)
        if (k + 1 < NCH) {
            const float* xn = xb + (size_t)(k + 1) * 24 * CC;
            #pragma unroll
            for (int kk = 0; kk < 3; ++kk) {
                const int r = rbase + 8 * kk;
                vbuf[kk] = *reinterpret_cast<const float2*>(xn + (size_t)r * CC);
            }
        }

        // compute the 2 staged windows
        #pragma unroll
        for (int w = 0; w < 2; ++w) {
            const int s = 2 * k + w;
            float x12[12];
            #pragma unroll
            for (int t = 0; t < 12; ++t) x12[t] = sl[cc * LSTR + w * 12 + t];

            const float u1 = x12[1] + x12[11], v1 = x12[1] - x12[11];
            const float u2 = x12[2] + x12[10], v2 = x12[2] - x12[10];
            const float u3 = x12[3] + x12[9],  v3 = x12[3] - x12[9];
            const float u4 = x12[4] + x12[8],  v4 = x12[4] - x12[8];
            const float u5 = x12[5] + x12[7],  v5 = x12[5] - x12[7];
            msum += (x12[0] + x12[6]) + ((u1 + u2) + (u3 + u4) + u5);

            float wa0, wp0, wa1, wp1;
            if (TRANS) {
                const float4 wv = wq[(size_t)(s * 4 + pg) * CC + cl];
                wa0 = wv.x; wp0 = wv.y; wa1 = wv.z; wp1 = wv.w;
            } else {
                const int p0 = pg, p1 = pg + 4;
                wa0 = wA_raw[((size_t)cl * S_OUT + p0) * S_IN + s];
                wp0 = wP_raw[((size_t)cl * S_OUT + p0) * S_IN + s];
                wa1 = wA_raw[((size_t)cl * S_OUT + p1) * S_IN + s];
                wp1 = wP_raw[((size_t)cl * S_OUT + p1) * S_IN + s];
                sw[0] += wa0; sw[1] += wa1;
            }

            A0[0] = fmaf(wa0, x12[0], A0[0]);
            A6[0] = fmaf(wa0, x12[6], A6[0]);
            Au[0][0] = fmaf(wa0, u1, Au[0][0]);
            Au[0][1] = fmaf(wa0, u2, Au[0][1]);
            Au[0][2] = fmaf(wa0, u3, Au[0][2]);
            Au[0][3] = fmaf(wa0, u4, Au[0][3]);
            Au[0][4] = fmaf(wa0, u5, Au[0][4]);
            Pv[0][0] = fmaf(wp0, v1, Pv[0][0]);
            Pv[0][1] = fmaf(wp0, v2, Pv[0][1]);
            Pv[0][2] = fmaf(wp0, v3, Pv[0][2]);
            Pv[0][3] = fmaf(wp0, v4, Pv[0][3]);
            Pv[0][4] = fmaf(wp0, v5, Pv[0][4]);

            A0[1] = fmaf(wa1, x12[0], A0[1]);
            A6[1] = fmaf(wa1, x12[6], A6[1]);
            Au[1][0] = fmaf(wa1, u1, Au[1][0]);
            Au[1][1] = fmaf(wa1, u2, Au[1][1]);
            Au[1][2] = fmaf(wa1, u3, Au[1][2]);
            Au[1][3] = fmaf(wa1, u4, Au[1][3]);
            Au[1][4] = fmaf(wa1, u5, Au[1][4]);
            Pv[1][0] = fmaf(wp1, v1, Pv[1][0]);
            Pv[1][1] = fmaf(wp1, v2, Pv[1][1]);
            Pv[1][2] = fmaf(wp1, v3, Pv[1][2]);
            Pv[1][3] = fmaf(wp1, v4, Pv[1][3]);
            Pv[1][4] = fmaf(wp1, v5, Pv[1][4]);
        }
    }

    if (!act) return;

    const float mean = msum * (1.0f / LL);

    #pragma unroll
    for (int e = 0; e < 2; ++e) {
        const int p = pg + 4 * e;
        float mc, bias[12];
        if (TRANS) {
            mc = mcoefT[p * CC + c];
            #pragma unroll
            for (int t = 0; t < 12; ++t)
                bias[t] = biasv[(size_t)(t * S_OUT + p) * CC + c];
        } else {
            mc = 1.0f - sw[e];
            const float ba = bAr[c * S_OUT + p], bp = bPr[c * S_OUT + p];
            #pragma unroll
            for (int t = 0; t < 12; ++t)
                bias[t] = COEFP[t] * bp + (t == 0 ? SQRT12F * ba : 0.f);
        }
        const float mb = mean * mc;
        float* ob = out + ((size_t)b * PRED + p * WIN) * CC + c;
        ob[0]              = A0[e] + mb + bias[0];
        ob[(size_t)6 * CC] = A6[e] + mb + bias[6];
        #pragma unroll
        for (int t = 1; t <= 5; ++t) {
            ob[(size_t)t * CC]        = 0.5f * (Au[e][t-1] + Pv[e][t-1]) + mb + bias[t];
            ob[(size_t)(12 - t) * CC] = 0.5f * (Au[e][t-1] - Pv[e][t-1]) + mb + bias[12 - t];
        }
    }
}

extern "C" void kernel_launch(void* const* d_in, const int* in_sizes, int n_in,
                              void* d_out, int out_size, void* d_ws, size_t ws_size,
                              hipStream_t stream) {
    const float* x  = (const float*)d_in[0];
    const float* wA = (const float*)d_in[1];
    const float* bA = (const float*)d_in[2];
    const float* wP = (const float*)d_in[3];
    const float* bP = (const float*)d_in[4];
    float* out = (float*)d_out;

    const size_t nW4 = (size_t)S_IN * 4 * CC * 4;    // 386176 floats (= 2*nW)
    const size_t nM  = (size_t)S_OUT * CC;           // 6896
    const size_t nBv = (size_t)12 * S_OUT * CC;      // 82752
    const size_t need = (nW4 + nM + nBv) * sizeof(float);

    dim3 grid(NTILES, BB);

    if (ws_size >= need) {
        float* wq4    = (float*)d_ws;                // nW4 floats
        float* mcoefT = wq4 + nW4;
        float* biasv  = mcoefT + nM;

        prep_wq4<<<(int)((nW4 + 255) / 256), 256, 0, stream>>>(wA, wP, wq4);
        prep_mcoef<<<(int)((nM + 255) / 256), 256, 0, stream>>>(wA, mcoefT);
        prep_bias<<<(int)((nBv + 255) / 256), 256, 0, stream>>>(bA, bP, biasv);

        fused19<true><<<grid, 512, 0, stream>>>(
            x, wq4, mcoefT, biasv,
            nullptr, nullptr, nullptr, nullptr, out);
    } else {
        fused19<false><<<grid, 512, 0, stream>>>(
            x, nullptr, nullptr, nullptr,
            wA, wP, bA, bP, out);
    }
}

// Round 20
// 65.556 us; speedup vs baseline: 1.0845x; 1.0845x over previous
//
#include <hip/hip_runtime.h>

#define BB 128
#define LL 336
#define CC 862
#define PRED 96
#define WIN 12
#define S_IN 28
#define S_OUT 8
#define CT 128
#define NTILES 7                       // ceil(862/128)
#define NCH 14                         // s-chunks of 2 windows (24 rows)
#define LSTR 25                        // LDS per-channel stride (odd -> conflict-free reads)

#define SQRT12F 3.4641016151377544f

// -Sb(t)/sqrt(12), Sb(t) = 2*sum_{k=1..5} sin(pi*k*t/6)   (exact closed forms)
__device__ const float COEFP[12] = {
    0.0f, -2.1547005383792515f, 0.0f, -0.5773502691896258f,
    0.0f, -0.15470053837925146f, 0.0f, 0.15470053837925146f,
    0.0f,  0.5773502691896258f, 0.0f,  2.1547005383792515f
};

// ---- prep kernels ----

// packed weights: wpk[((p*S_IN + s)*CC + c)*2 + {0,1}] = {wA, wP}[c][p][s]
__global__ void prep_wpk(const float* __restrict__ wA, const float* __restrict__ wP,
                         float* __restrict__ wpk) {
    int i = blockIdx.x * 256 + threadIdx.x;          // i = (p*S_IN + s)*CC + c
    if (i >= S_OUT * S_IN * CC) return;
    int c  = i % CC;
    int ps = i / CC;
    int s  = ps % S_IN;
    int p  = ps / S_IN;
    int src = (c * S_OUT + p) * S_IN + s;
    wpk[2 * i]     = wA[src];
    wpk[2 * i + 1] = wP[src];
}

__global__ void prep_mcoef(const float* __restrict__ wA, float* __restrict__ mcoefT) {
    int i = blockIdx.x * 256 + threadIdx.x;          // [p][c]
    if (i >= S_OUT * CC) return;
    int c = i % CC;
    int p = i / CC;
    float s = 0.f;
    for (int k = 0; k < S_IN; ++k) s += wA[(c * S_OUT + p) * S_IN + k];
    mcoefT[i] = 1.0f - s;
}

__global__ void prep_bias(const float* __restrict__ bA, const float* __restrict__ bP,
                          float* __restrict__ biasv) {
    int i = blockIdx.x * 256 + threadIdx.x;          // [t][p][c]
    if (i >= 12 * S_OUT * CC) return;
    int c = i % CC;
    int tp = i / CC;
    int p = tp % S_OUT;
    int t = tp / S_OUT;
    float v = COEFP[t] * bP[c * S_OUT + p];
    if (t == 0) v += SQRT12F * bA[c * S_OUT + p];
    biasv[i] = v;
}

// ---- fused main kernel ----
// EXACTLY the r16 champion (59.1 us): CT=128 (512-B HBM granules — the lever
// that broke the 3 TB/s DRAM-pattern wall), 24-row chunks, single LDS buffer,
// 2 barriers/chunk, float2 packed weights.
// ONE change vs r16: launch_bounds(512,6) -> 3 resident blocks/CU (was 2);
// VGPR cap ~84 (r17's near-identical body compiled to 40 under this bound,
// no spill; r19 proved a 64-cap DOES spill this body -> reverted).

template <bool TRANS>
__global__ __launch_bounds__(512, 6) void fused20(
    const float* __restrict__ x,
    const float* __restrict__ wpk,
    const float* __restrict__ mcoefT, const float* __restrict__ biasv,
    const float* __restrict__ wA_raw, const float* __restrict__ wP_raw,
    const float* __restrict__ bAr, const float* __restrict__ bPr,
    float* __restrict__ out)
{
    __shared__ float sl[CT * LSTR];    // 12800 B

    const int b   = blockIdx.y;
    const int c0  = blockIdx.x * CT;
    const int NC  = min(CT, CC - c0);  // 128 or 94 (even)
    const int tid = threadIdx.x;       // 0..511

    // staging map: one wave = one full 512-B row segment (64 float2)
    const int slot  = tid & 63;
    const int rbase = tid >> 6;        // 0..7
    const int col   = 2 * slot;
    const int csrc  = (col + 1 < NC) ? col : (NC - 2);
    const float* xb = x + ((size_t)b * LL) * CC + c0 + csrc;

    // compute map
    const int cc = tid & 127;
    const int pg = tid >> 7;           // 0..3 -> p = pg, pg+4
    const int c  = c0 + cc;
    const bool act = (cc < NC);
    const int cl = act ? c : (CC - 1);

    // prologue: issue chunk 0 loads (rows 0..23)
    float2 vbuf[3];
    #pragma unroll
    for (int kk = 0; kk < 3; ++kk) {
        const int r = rbase + 8 * kk;
        vbuf[kk] = *reinterpret_cast<const float2*>(xb + (size_t)r * CC);
    }

    float A0[2] = {0.f, 0.f}, A6[2] = {0.f, 0.f};
    float Au[2][5] = {{0.f,0.f,0.f,0.f,0.f},{0.f,0.f,0.f,0.f,0.f}};
    float Pv[2][5] = {{0.f,0.f,0.f,0.f,0.f},{0.f,0.f,0.f,0.f,0.f}};
    float msum = 0.f;
    float sw[2] = {0.f, 0.f};          // fallback only

    const float2* wq = reinterpret_cast<const float2*>(wpk);

    #pragma unroll 1
    for (int k = 0; k < NCH; ++k) {
        __syncthreads();               // previous compute done reading sl
        #pragma unroll
        for (int kk = 0; kk < 3; ++kk) {
            const int r = rbase + 8 * kk;
            sl[col * LSTR + r]       = vbuf[kk].x;
            sl[(col + 1) * LSTR + r] = vbuf[kk].y;
        }
        __syncthreads();               // sl ready

        // prefetch next chunk (overlaps compute below)
        if (k + 1 < NCH) {
            const float* xn = xb + (size_t)(k + 1) * 24 * CC;
            #pragma unroll
            for (int kk = 0; kk < 3; ++kk) {
                const int r = rbase + 8 * kk;
                vbuf[kk] = *reinterpret_cast<const float2*>(xn + (size_t)r * CC);
            }
        }

        // compute the 2 staged windows
        #pragma unroll
        for (int w = 0; w < 2; ++w) {
            const int s = 2 * k + w;
            float x12[12];
            #pragma unroll
            for (int t = 0; t < 12; ++t) x12[t] = sl[cc * LSTR + w * 12 + t];

            const float u1 = x12[1] + x12[11], v1 = x12[1] - x12[11];
            const float u2 = x12[2] + x12[10], v2 = x12[2] - x12[10];
            const float u3 = x12[3] + x12[9],  v3 = x12[3] - x12[9];
            const float u4 = x12[4] + x12[8],  v4 = x12[4] - x12[8];
            const float u5 = x12[5] + x12[7],  v5 = x12[5] - x12[7];
            msum += (x12[0] + x12[6]) + ((u1 + u2) + (u3 + u4) + u5);

            #pragma unroll
            for (int e = 0; e < 2; ++e) {
                const int p = pg + 4 * e;
                float wa, wpv;
                if (TRANS) {
                    const float2 wv = wq[(size_t)(p * S_IN + s) * CC + cl];
                    wa = wv.x; wpv = wv.y;
                } else {
                    wa  = wA_raw[((size_t)cl * S_OUT + p) * S_IN + s];
                    wpv = wP_raw[((size_t)cl * S_OUT + p) * S_IN + s];
                    sw[e] += wa;
                }
                A0[e] = fmaf(wa, x12[0], A0[e]);
                A6[e] = fmaf(wa, x12[6], A6[e]);
                Au[e][0] = fmaf(wa, u1, Au[e][0]);
                Au[e][1] = fmaf(wa, u2, Au[e][1]);
                Au[e][2] = fmaf(wa, u3, Au[e][2]);
                Au[e][3] = fmaf(wa, u4, Au[e][3]);
                Au[e][4] = fmaf(wa, u5, Au[e][4]);
                Pv[e][0] = fmaf(wpv, v1, Pv[e][0]);
                Pv[e][1] = fmaf(wpv, v2, Pv[e][1]);
                Pv[e][2] = fmaf(wpv, v3, Pv[e][2]);
                Pv[e][3] = fmaf(wpv, v4, Pv[e][3]);
                Pv[e][4] = fmaf(wpv, v5, Pv[e][4]);
            }
        }
    }

    if (!act) return;

    const float mean = msum * (1.0f / LL);

    #pragma unroll
    for (int e = 0; e < 2; ++e) {
        const int p = pg + 4 * e;
        float mc, bias[12];
        if (TRANS) {
            mc = mcoefT[p * CC + c];
            #pragma unroll
            for (int t = 0; t < 12; ++t)
                bias[t] = biasv[(size_t)(t * S_OUT + p) * CC + c];
        } else {
            mc = 1.0f - sw[e];
            const float ba = bAr[c * S_OUT + p], bp = bPr[c * S_OUT + p];
            #pragma unroll
            for (int t = 0; t < 12; ++t)
                bias[t] = COEFP[t] * bp + (t == 0 ? SQRT12F * ba : 0.f);
        }
        const float mb = mean * mc;
        float* ob = out + ((size_t)b * PRED + p * WIN) * CC + c;
        ob[0]              = A0[e] + mb + bias[0];
        ob[(size_t)6 * CC] = A6[e] + mb + bias[6];
        #pragma unroll
        for (int t = 1; t <= 5; ++t) {
            ob[(size_t)t * CC]        = 0.5f * (Au[e][t-1] + Pv[e][t-1]) + mb + bias[t];
            ob[(size_t)(12 - t) * CC] = 0.5f * (Au[e][t-1] - Pv[e][t-1]) + mb + bias[12 - t];
        }
    }
}

extern "C" void kernel_launch(void* const* d_in, const int* in_sizes, int n_in,
                              void* d_out, int out_size, void* d_ws, size_t ws_size,
                              hipStream_t stream) {
    const float* x  = (const float*)d_in[0];
    const float* wA = (const float*)d_in[1];
    const float* bA = (const float*)d_in[2];
    const float* wP = (const float*)d_in[3];
    const float* bP = (const float*)d_in[4];
    float* out = (float*)d_out;

    const size_t nW  = (size_t)S_OUT * S_IN * CC;    // 193088
    const size_t nM  = (size_t)S_OUT * CC;           // 6896
    const size_t nBv = (size_t)12 * S_OUT * CC;      // 82752
    const size_t need = (2 * nW + nM + nBv) * sizeof(float);

    dim3 grid(NTILES, BB);

    if (ws_size >= need) {
        float* wpk    = (float*)d_ws;                // 2*nW floats
        float* mcoefT = wpk + 2 * nW;
        float* biasv  = mcoefT + nM;

        prep_wpk<<<(int)((nW + 255) / 256), 256, 0, stream>>>(wA, wP, wpk);
        prep_mcoef<<<(int)((nM + 255) / 256), 256, 0, stream>>>(wA, mcoefT);
        prep_bias<<<(int)((nBv + 255) / 256), 256, 0, stream>>>(bA, bP, biasv);

        fused20<true><<<grid, 512, 0, stream>>>(
            x, wpk, mcoefT, biasv,
            nullptr, nullptr, nullptr, nullptr, out);
    } else {
        fused20<false><<<grid, 512, 0, stream>>>(
            x, nullptr, nullptr, nullptr,
            wA, wP, bA, bP, out);
    }
}

// Round 21
// 62.966 us; speedup vs baseline: 1.1291x; 1.0411x over previous
//
#include <hip/hip_runtime.h>

#define BB 128
#define LL 336
#define CC 862
#define PRED 96
#define WIN 12
#define S_IN 28
#define S_OUT 8
#define CT 256
#define NTILES 4                       // ceil(862/256): 3 full + 94-ch remainder
#define NCH 14                         // s-chunks of 2 windows (24 rows)
#define LSTR 25                        // LDS per-channel stride (odd -> conflict-free reads)

#define SQRT12F 3.4641016151377544f

// -Sb(t)/sqrt(12), Sb(t) = 2*sum_{k=1..5} sin(pi*k*t/6)   (exact closed forms)
__device__ const float COEFP[12] = {
    0.0f, -2.1547005383792515f, 0.0f, -0.5773502691896258f,
    0.0f, -0.15470053837925146f, 0.0f, 0.15470053837925146f,
    0.0f,  0.5773502691896258f, 0.0f,  2.1547005383792515f
};

// ---- prep kernels ----

// packed weights: wpk[((p*S_IN + s)*CC + c)*2 + {0,1}] = {wA, wP}[c][p][s]
__global__ void prep_wpk(const float* __restrict__ wA, const float* __restrict__ wP,
                         float* __restrict__ wpk) {
    int i = blockIdx.x * 256 + threadIdx.x;          // i = (p*S_IN + s)*CC + c
    if (i >= S_OUT * S_IN * CC) return;
    int c  = i % CC;
    int ps = i / CC;
    int s  = ps % S_IN;
    int p  = ps / S_IN;
    int src = (c * S_OUT + p) * S_IN + s;
    wpk[2 * i]     = wA[src];
    wpk[2 * i + 1] = wP[src];
}

__global__ void prep_mcoef(const float* __restrict__ wA, float* __restrict__ mcoefT) {
    int i = blockIdx.x * 256 + threadIdx.x;          // [p][c]
    if (i >= S_OUT * CC) return;
    int c = i % CC;
    int p = i / CC;
    float s = 0.f;
    for (int k = 0; k < S_IN; ++k) s += wA[(c * S_OUT + p) * S_IN + k];
    mcoefT[i] = 1.0f - s;
}

__global__ void prep_bias(const float* __restrict__ bA, const float* __restrict__ bP,
                          float* __restrict__ biasv) {
    int i = blockIdx.x * 256 + threadIdx.x;          // [t][p][c]
    if (i >= 12 * S_OUT * CC) return;
    int c = i % CC;
    int tp = i / CC;
    int p = tp % S_OUT;
    int t = tp / S_OUT;
    float v = COEFP[t] * bP[c * S_OUT + p];
    if (t == 0) v += SQRT12F * bA[c * S_OUT + p];
    biasv[i] = v;
}

// ---- fused main kernel ----
// r16 structure with ONE lever moved: CT=128 -> 256, i.e. 512-B -> 1024-B
// contiguous HBM granules (granule width was the only lever that ever broke
// a plateau: 128B->512B = 86->59 us). Thread = (cc 0..255, pg 0..1), owns
// p = pg + 2e (e=0..3): 48 static accumulators (~90-100 VGPR, under (512,4)'s
// 128 cap which r16 proved schedules without spill).

template <bool TRANS>
__global__ __launch_bounds__(512, 4) void fused21(
    const float* __restrict__ x,
    const float* __restrict__ wpk,
    const float* __restrict__ mcoefT, const float* __restrict__ biasv,
    const float* __restrict__ wA_raw, const float* __restrict__ wP_raw,
    const float* __restrict__ bAr, const float* __restrict__ bPr,
    float* __restrict__ out)
{
    __shared__ float sl[CT * LSTR];    // 25600 B

    const int b   = blockIdx.y;
    const int c0  = blockIdx.x * CT;
    const int NC  = min(CT, CC - c0);  // 256 or 94 (even)
    const int tid = threadIdx.x;       // 0..511

    // staging map: 128 consecutive threads = one 1024-B row segment (128 float2)
    const int slot  = tid & 127;
    const int rbase = tid >> 7;        // 0..3
    const int col   = 2 * slot;
    const int csrc  = (col + 1 < NC) ? col : (NC - 2);
    const float* xb = x + ((size_t)b * LL) * CC + c0 + csrc;

    // compute map
    const int cc = tid & 255;
    const int pg = tid >> 8;           // 0..1 -> p = pg + 2e, e = 0..3
    const int c  = c0 + cc;
    const bool act = (cc < NC);
    const int cl = act ? c : (CC - 1);

    // prologue: issue chunk 0 loads (rows 0..23, 6 per thread)
    float2 vbuf[6];
    #pragma unroll
    for (int kk = 0; kk < 6; ++kk) {
        const int r = rbase + 4 * kk;
        vbuf[kk] = *reinterpret_cast<const float2*>(xb + (size_t)r * CC);
    }

    float A0[4] = {0.f,0.f,0.f,0.f}, A6[4] = {0.f,0.f,0.f,0.f};
    float Au[4][5] = {{0.f,0.f,0.f,0.f,0.f},{0.f,0.f,0.f,0.f,0.f},
                      {0.f,0.f,0.f,0.f,0.f},{0.f,0.f,0.f,0.f,0.f}};
    float Pv[4][5] = {{0.f,0.f,0.f,0.f,0.f},{0.f,0.f,0.f,0.f,0.f},
                      {0.f,0.f,0.f,0.f,0.f},{0.f,0.f,0.f,0.f,0.f}};
    float msum = 0.f;
    float sw[4] = {0.f,0.f,0.f,0.f};   // fallback only

    const float2* wq = reinterpret_cast<const float2*>(wpk);

    #pragma unroll 1
    for (int k = 0; k < NCH; ++k) {
        __syncthreads();               // previous compute done reading sl
        #pragma unroll
        for (int kk = 0; kk < 6; ++kk) {
            const int r = rbase + 4 * kk;
            sl[col * LSTR + r]       = vbuf[kk].x;
            sl[(col + 1) * LSTR + r] = vbuf[kk].y;
        }
        __syncthreads();               // sl ready

        // prefetch next chunk (overlaps compute below)
        if (k + 1 < NCH) {
            const float* xn = xb + (size_t)(k + 1) * 24 * CC;
            #pragma unroll
            for (int kk = 0; kk < 6; ++kk) {
                const int r = rbase + 4 * kk;
                vbuf[kk] = *reinterpret_cast<const float2*>(xn + (size_t)r * CC);
            }
        }

        // compute the 2 staged windows
        #pragma unroll
        for (int w = 0; w < 2; ++w) {
            const int s = 2 * k + w;
            float x12[12];
            #pragma unroll
            for (int t = 0; t < 12; ++t) x12[t] = sl[cc * LSTR + w * 12 + t];

            const float u1 = x12[1] + x12[11], v1 = x12[1] - x12[11];
            const float u2 = x12[2] + x12[10], v2 = x12[2] - x12[10];
            const float u3 = x12[3] + x12[9],  v3 = x12[3] - x12[9];
            const float u4 = x12[4] + x12[8],  v4 = x12[4] - x12[8];
            const float u5 = x12[5] + x12[7],  v5 = x12[5] - x12[7];
            msum += (x12[0] + x12[6]) + ((u1 + u2) + (u3 + u4) + u5);

            #pragma unroll
            for (int e = 0; e < 4; ++e) {
                const int p = pg + 2 * e;
                float wa, wpv;
                if (TRANS) {
                    const float2 wv = wq[(size_t)(p * S_IN + s) * CC + cl];
                    wa = wv.x; wpv = wv.y;
                } else {
                    wa  = wA_raw[((size_t)cl * S_OUT + p) * S_IN + s];
                    wpv = wP_raw[((size_t)cl * S_OUT + p) * S_IN + s];
                    sw[e] += wa;
                }
                A0[e] = fmaf(wa, x12[0], A0[e]);
                A6[e] = fmaf(wa, x12[6], A6[e]);
                Au[e][0] = fmaf(wa, u1, Au[e][0]);
                Au[e][1] = fmaf(wa, u2, Au[e][1]);
                Au[e][2] = fmaf(wa, u3, Au[e][2]);
                Au[e][3] = fmaf(wa, u4, Au[e][3]);
                Au[e][4] = fmaf(wa, u5, Au[e][4]);
                Pv[e][0] = fmaf(wpv, v1, Pv[e][0]);
                Pv[e][1] = fmaf(wpv, v2, Pv[e][1]);
                Pv[e][2] = fmaf(wpv, v3, Pv[e][2]);
                Pv[e][3] = fmaf(wpv, v4, Pv[e][3]);
                Pv[e][4] = fmaf(wpv, v5, Pv[e][4]);
            }
        }
    }

    if (!act) return;

    const float mean = msum * (1.0f / LL);

    #pragma unroll
    for (int e = 0; e < 4; ++e) {
        const int p = pg + 2 * e;
        float mc, bias[12];
        if (TRANS) {
            mc = mcoefT[p * CC + c];
            #pragma unroll
            for (int t = 0; t < 12; ++t)
                bias[t] = biasv[(size_t)(t * S_OUT + p) * CC + c];
        } else {
            mc = 1.0f - sw[e];
            const float ba = bAr[c * S_OUT + p], bp = bPr[c * S_OUT + p];
            #pragma unroll
            for (int t = 0; t < 12; ++t)
                bias[t] = COEFP[t] * bp + (t == 0 ? SQRT12F * ba : 0.f);
        }
        const float mb = mean * mc;
        float* ob = out + ((size_t)b * PRED + p * WIN) * CC + c;
        ob[0]              = A0[e] + mb + bias[0];
        ob[(size_t)6 * CC] = A6[e] + mb + bias[6];
        #pragma unroll
        for (int t = 1; t <= 5; ++t) {
            ob[(size_t)t * CC]        = 0.5f * (Au[e][t-1] + Pv[e][t-1]) + mb + bias[t];
            ob[(size_t)(12 - t) * CC] = 0.5f * (Au[e][t-1] - Pv[e][t-1]) + mb + bias[12 - t];
        }
    }
}

extern "C" void kernel_launch(void* const* d_in, const int* in_sizes, int n_in,
                              void* d_out, int out_size, void* d_ws, size_t ws_size,
                              hipStream_t stream) {
    const float* x  = (const float*)d_in[0];
    const float* wA = (const float*)d_in[1];
    const float* bA = (const float*)d_in[2];
    const float* wP = (const float*)d_in[3];
    const float* bP = (const float*)d_in[4];
    float* out = (float*)d_out;

    const size_t nW  = (size_t)S_OUT * S_IN * CC;    // 193088
    const size_t nM  = (size_t)S_OUT * CC;           // 6896
    const size_t nBv = (size_t)12 * S_OUT * CC;      // 82752
    const size_t need = (2 * nW + nM + nBv) * sizeof(float);

    dim3 grid(NTILES, BB);

    if (ws_size >= need) {
        float* wpk    = (float*)d_ws;                // 2*nW floats
        float* mcoefT = wpk + 2 * nW;
        float* biasv  = mcoefT + nM;

        prep_wpk<<<(int)((nW + 255) / 256), 256, 0, stream>>>(wA, wP, wpk);
        prep_mcoef<<<(int)((nM + 255) / 256), 256, 0, stream>>>(wA, mcoefT);
        prep_bias<<<(int)((nBv + 255) / 256), 256, 0, stream>>>(bA, bP, biasv);

        fused21<true><<<grid, 512, 0, stream>>>(
            x, wpk, mcoefT, biasv,
            nullptr, nullptr, nullptr, nullptr, out);
    } else {
        fused21<false><<<grid, 512, 0, stream>>>(
            x, nullptr, nullptr, nullptr,
            wA, wP, bA, bP, out);
    }
}

// Round 22
// 58.087 us; speedup vs baseline: 1.2239x; 1.0840x over previous
//
#include <hip/hip_runtime.h>

#define BB 128
#define LL 336
#define CC 862
#define PRED 96
#define WIN 12
#define S_IN 28
#define S_OUT 8
#define CT 128
#define NTILES 7                       // ceil(862/128)
#define NCH 14                         // s-chunks of 2 windows (24 rows)
#define LSTR 25                        // LDS per-channel stride (odd -> conflict-free reads)

#define SQRT12F 3.4641016151377544f

// -Sb(t)/sqrt(12), Sb(t) = 2*sum_{k=1..5} sin(pi*k*t/6)   (exact closed forms)
__device__ const float COEFP[12] = {
    0.0f, -2.1547005383792515f, 0.0f, -0.5773502691896258f,
    0.0f, -0.15470053837925146f, 0.0f, 0.15470053837925146f,
    0.0f,  0.5773502691896258f, 0.0f,  2.1547005383792515f
};

// ---- prep kernels ----

// packed weights: wpk[((p*S_IN + s)*CC + c)*2 + {0,1}] = {wA, wP}[c][p][s]
__global__ void prep_wpk(const float* __restrict__ wA, const float* __restrict__ wP,
                         float* __restrict__ wpk) {
    int i = blockIdx.x * 256 + threadIdx.x;          // i = (p*S_IN + s)*CC + c
    if (i >= S_OUT * S_IN * CC) return;
    int c  = i % CC;
    int ps = i / CC;
    int s  = ps % S_IN;
    int p  = ps / S_IN;
    int src = (c * S_OUT + p) * S_IN + s;
    wpk[2 * i]     = wA[src];
    wpk[2 * i + 1] = wP[src];
}

__global__ void prep_mcoef(const float* __restrict__ wA, float* __restrict__ mcoefT) {
    int i = blockIdx.x * 256 + threadIdx.x;          // [p][c]
    if (i >= S_OUT * CC) return;
    int c = i % CC;
    int p = i / CC;
    float s = 0.f;
    for (int k = 0; k < S_IN; ++k) s += wA[(c * S_OUT + p) * S_IN + k];
    mcoefT[i] = 1.0f - s;
}

__global__ void prep_bias(const float* __restrict__ bA, const float* __restrict__ bP,
                          float* __restrict__ biasv) {
    int i = blockIdx.x * 256 + threadIdx.x;          // [t][p][c]
    if (i >= 12 * S_OUT * CC) return;
    int c = i % CC;
    int tp = i / CC;
    int p = tp % S_OUT;
    int t = tp / S_OUT;
    float v = COEFP[t] * bP[c * S_OUT + p];
    if (t == 0) v += SQRT12F * bA[c * S_OUT + p];
    biasv[i] = v;
}

// ---- fused main kernel ----
// The r16 champion, byte-identical (59.1 us measured):
// CT=128 -> 512-B contiguous HBM granules (the lever that broke the 3 TB/s
// DRAM-pattern wall; 64 B / 128 B / 1024 B all measurably worse).
// 24-row chunks, single LDS buffer (dbuf regressed), 2 barriers/chunk
// (chunk=48 regressed), launch_bounds(512,4) (tighter caps spill or
// deoptimize scheduling), float2 packed weights (b128 confounded w/ spill).
// 512 thr = (cc 0..127, pg 0..3); thread owns p = pg, pg+4.

template <bool TRANS>
__global__ __launch_bounds__(512, 4) void fused16(
    const float* __restrict__ x,
    const float* __restrict__ wpk,
    const float* __restrict__ mcoefT, const float* __restrict__ biasv,
    const float* __restrict__ wA_raw, const float* __restrict__ wP_raw,
    const float* __restrict__ bAr, const float* __restrict__ bPr,
    float* __restrict__ out)
{
    __shared__ float sl[CT * LSTR];    // 12800 B

    const int b   = blockIdx.y;
    const int c0  = blockIdx.x * CT;
    const int NC  = min(CT, CC - c0);  // 128 or 94 (even)
    const int tid = threadIdx.x;       // 0..511

    // staging map: one wave = one full 512-B row segment (64 float2)
    const int slot  = tid & 63;
    const int rbase = tid >> 6;        // 0..7
    const int col   = 2 * slot;
    const int csrc  = (col + 1 < NC) ? col : (NC - 2);
    const float* xb = x + ((size_t)b * LL) * CC + c0 + csrc;

    // compute map
    const int cc = tid & 127;
    const int pg = tid >> 7;           // 0..3 -> p = pg, pg+4
    const int c  = c0 + cc;
    const bool act = (cc < NC);
    const int cl = act ? c : (CC - 1);

    // prologue: issue chunk 0 loads (rows 0..23)
    float2 vbuf[3];
    #pragma unroll
    for (int kk = 0; kk < 3; ++kk) {
        const int r = rbase + 8 * kk;
        vbuf[kk] = *reinterpret_cast<const float2*>(xb + (size_t)r * CC);
    }

    float A0[2] = {0.f, 0.f}, A6[2] = {0.f, 0.f};
    float Au[2][5] = {{0.f,0.f,0.f,0.f,0.f},{0.f,0.f,0.f,0.f,0.f}};
    float Pv[2][5] = {{0.f,0.f,0.f,0.f,0.f},{0.f,0.f,0.f,0.f,0.f}};
    float msum = 0.f;
    float sw[2] = {0.f, 0.f};          // fallback only

    const float2* wq = reinterpret_cast<const float2*>(wpk);

    #pragma unroll 1
    for (int k = 0; k < NCH; ++k) {
        __syncthreads();               // previous compute done reading sl
        #pragma unroll
        for (int kk = 0; kk < 3; ++kk) {
            const int r = rbase + 8 * kk;
            sl[col * LSTR + r]       = vbuf[kk].x;
            sl[(col + 1) * LSTR + r] = vbuf[kk].y;
        }
        __syncthreads();               // sl ready

        // prefetch next chunk (overlaps compute below)
        if (k + 1 < NCH) {
            const float* xn = xb + (size_t)(k + 1) * 24 * CC;
            #pragma unroll
            for (int kk = 0; kk < 3; ++kk) {
                const int r = rbase + 8 * kk;
                vbuf[kk] = *reinterpret_cast<const float2*>(xn + (size_t)r * CC);
            }
        }

        // compute the 2 staged windows
        #pragma unroll
        for (int w = 0; w < 2; ++w) {
            const int s = 2 * k + w;
            float x12[12];
            #pragma unroll
            for (int t = 0; t < 12; ++t) x12[t] = sl[cc * LSTR + w * 12 + t];

            const float u1 = x12[1] + x12[11], v1 = x12[1] - x12[11];
            const float u2 = x12[2] + x12[10], v2 = x12[2] - x12[10];
            const float u3 = x12[3] + x12[9],  v3 = x12[3] - x12[9];
            const float u4 = x12[4] + x12[8],  v4 = x12[4] - x12[8];
            const float u5 = x12[5] + x12[7],  v5 = x12[5] - x12[7];
            msum += (x12[0] + x12[6]) + ((u1 + u2) + (u3 + u4) + u5);

            #pragma unroll
            for (int e = 0; e < 2; ++e) {
                const int p = pg + 4 * e;
                float wa, wpv;
                if (TRANS) {
                    const float2 wv = wq[(size_t)(p * S_IN + s) * CC + cl];
                    wa = wv.x; wpv = wv.y;
                } else {
                    wa  = wA_raw[((size_t)cl * S_OUT + p) * S_IN + s];
                    wpv = wP_raw[((size_t)cl * S_OUT + p) * S_IN + s];
                    sw[e] += wa;
                }
                A0[e] = fmaf(wa, x12[0], A0[e]);
                A6[e] = fmaf(wa, x12[6], A6[e]);
                Au[e][0] = fmaf(wa, u1, Au[e][0]);
                Au[e][1] = fmaf(wa, u2, Au[e][1]);
                Au[e][2] = fmaf(wa, u3, Au[e][2]);
                Au[e][3] = fmaf(wa, u4, Au[e][3]);
                Au[e][4] = fmaf(wa, u5, Au[e][4]);
                Pv[e][0] = fmaf(wpv, v1, Pv[e][0]);
                Pv[e][1] = fmaf(wpv, v2, Pv[e][1]);
                Pv[e][2] = fmaf(wpv, v3, Pv[e][2]);
                Pv[e][3] = fmaf(wpv, v4, Pv[e][3]);
                Pv[e][4] = fmaf(wpv, v5, Pv[e][4]);
            }
        }
    }

    if (!act) return;

    const float mean = msum * (1.0f / LL);

    #pragma unroll
    for (int e = 0; e < 2; ++e) {
        const int p = pg + 4 * e;
        float mc, bias[12];
        if (TRANS) {
            mc = mcoefT[p * CC + c];
            #pragma unroll
            for (int t = 0; t < 12; ++t)
                bias[t] = biasv[(size_t)(t * S_OUT + p) * CC + c];
        } else {
            mc = 1.0f - sw[e];
            const float ba = bAr[c * S_OUT + p], bp = bPr[c * S_OUT + p];
            #pragma unroll
            for (int t = 0; t < 12; ++t)
                bias[t] = COEFP[t] * bp + (t == 0 ? SQRT12F * ba : 0.f);
        }
        const float mb = mean * mc;
        float* ob = out + ((size_t)b * PRED + p * WIN) * CC + c;
        ob[0]              = A0[e] + mb + bias[0];
        ob[(size_t)6 * CC] = A6[e] + mb + bias[6];
        #pragma unroll
        for (int t = 1; t <= 5; ++t) {
            ob[(size_t)t * CC]        = 0.5f * (Au[e][t-1] + Pv[e][t-1]) + mb + bias[t];
            ob[(size_t)(12 - t) * CC] = 0.5f * (Au[e][t-1] - Pv[e][t-1]) + mb + bias[12 - t];
        }
    }
}

extern "C" void kernel_launch(void* const* d_in, const int* in_sizes, int n_in,
                              void* d_out, int out_size, void* d_ws, size_t ws_size,
                              hipStream_t stream) {
    const float* x  = (const float*)d_in[0];
    const float* wA = (const float*)d_in[1];
    const float* bA = (const float*)d_in[2];
    const float* wP = (const float*)d_in[3];
    const float* bP = (const float*)d_in[4];
    float* out = (float*)d_out;

    const size_t nW  = (size_t)S_OUT * S_IN * CC;    // 193088
    const size_t nM  = (size_t)S_OUT * CC;           // 6896
    const size_t nBv = (size_t)12 * S_OUT * CC;      // 82752
    const size_t need = (2 * nW + nM + nBv) * sizeof(float);

    dim3 grid(NTILES, BB);

    if (ws_size >= need) {
        float* wpk    = (float*)d_ws;                // 2*nW floats
        float* mcoefT = wpk + 2 * nW;
        float* biasv  = mcoefT + nM;

        prep_wpk<<<(int)((nW + 255) / 256), 256, 0, stream>>>(wA, wP, wpk);
        prep_mcoef<<<(int)((nM + 255) / 256), 256, 0, stream>>>(wA, mcoefT);
        prep_bias<<<(int)((nBv + 255) / 256), 256, 0, stream>>>(bA, bP, biasv);

        fused16<true><<<grid, 512, 0, stream>>>(
            x, wpk, mcoefT, biasv,
            nullptr, nullptr, nullptr, nullptr, out);
    } else {
        fused16<false><<<grid, 512, 0, stream>>>(
            x, nullptr, nullptr, nullptr,
            wA, wP, bA, bP, out);
    }
}